// Round 9
// baseline (236.832 us; speedup 1.0000x reference)
//
#include <hip/hip_runtime.h>

#define VOCAB 50000
#define BROWS 4096
#define F 64
#define NCOLS 80            // 64 features + w_hi + w_lo + 14 zero pad
#define NT 5                // n-tiles of 16
#define SPLITS 16
#define NR 98               // K-tiles (of 32) per split
#define KT_TOTAL (SPLITS * NR)            // 1568
#define KPAD (KT_TOTAL * 32)              // 50176
#define RDWORDS 1568                      // packed dwords per row (= KPAD/32)
#define SPANS 25                          // 2048-elem spans per row (24 full + tail)

#define AS1 __attribute__((address_space(1)))
#define AS3 __attribute__((address_space(3)))

typedef __attribute__((ext_vector_type(4))) float f32x4;
typedef __attribute__((ext_vector_type(8))) short s16x8;

__device__ __forceinline__ unsigned short f2bf(float f) {
    unsigned u = __builtin_bit_cast(unsigned, f);
    unsigned r = (u + 0x7FFFu + ((u >> 16) & 1u)) >> 16;   // round-to-nearest-even
    return (unsigned short)r;
}
__device__ __forceinline__ float bf2f(unsigned short b) {
    unsigned u = ((unsigned)b) << 16;
    return __builtin_bit_cast(float, u);
}

// --- kernel 0: bit-pack x with a COPY-SHAPED read ---
// Wave W packs span s of row m (2048 elems): iteration j, lane l reads
// x[m][2048 s + 64 j + l] (scalar dword, 256B dense per instruction);
// __ballot(v&1) = 64 consecutive bits; lane 2j keeps lo32, lane 2j+1 hi32.
// One coalesced 256B store (64 dwords) per wave. K-pad dwords = 0.
__global__ void fm_pack(const int* __restrict__ x, unsigned* __restrict__ xb) {
    const int W = blockIdx.x * 4 + (threadIdx.x >> 6);     // global wave id
    const int lane = threadIdx.x & 63;
    const int row = W / SPANS;
    const int span = W - row * SPANS;
    const int* __restrict__ xr = x + (size_t)row * VOCAB + span * 2048;
    unsigned my = 0;
    if (span < SPANS - 1) {                                 // full span
#pragma unroll
        for (int j = 0; j < 32; ++j) {
            int v = xr[j * 64 + lane];
            unsigned long long m = __ballot(v & 1);
            if ((lane >> 1) == j) my = (lane & 1) ? (unsigned)(m >> 32) : (unsigned)m;
        }
        xb[(size_t)row * RDWORDS + span * 64 + lane] = my;
    } else {                                                // tail: elems 49152..50000
        const int base = (SPANS - 1) * 2048;                // 49152
#pragma unroll
        for (int j = 0; j < 14; ++j) {                      // j>=14 -> all pad (0)
            int idx = base + j * 64 + lane;
            int v = (idx < VOCAB) ? xr[j * 64 + lane] : 0;
            unsigned long long m = __ballot(v & 1);
            if ((lane >> 1) == j) my = (lane & 1) ? (unsigned)(m >> 32) : (unsigned)m;
        }
        const int d = (SPANS - 1) * 64 + lane;              // 1536 + lane
        if (d < RDWORDS) xb[(size_t)row * RDWORDS + d] = my;
    }
}

// --- kernel 1: w[k] = bias[k] - 0.5*||V[k]||^2 (0 for padded k) ---
__global__ void fm_prep_w(const float* __restrict__ V, const float* __restrict__ bias,
                          float* __restrict__ w) {
    int k = blockIdx.x * blockDim.x + threadIdx.x;
    if (k >= KPAD) return;
    float val = 0.f;
    if (k < VOCAB) {
        const float4* row = reinterpret_cast<const float4*>(V + (size_t)k * F);
        float ss = 0.f;
#pragma unroll
        for (int j = 0; j < F / 4; ++j) {
            float4 v = row[j];
            ss += v.x * v.x + v.y * v.y + v.z * v.z + v.w * v.w;
        }
        val = bias[k] - 0.5f * ss;
    }
    w[k] = val;
}

// --- kernel 2: pack B operand into MFMA 16x16x32 bf16 fragment order ---
// bfrag[(kt*NT + nt)*64 + lane] = uint4 of 8 bf16:
//   elem j = B[kt*32 + (lane>>4)*8 + j][nt*16 + (lane&15)]
// where B[k][n] = V[k][n] (n<64), w_hi[k] (n==64), w_lo[k] (n==65), 0 otherwise.
__global__ void fm_prep_bfrag(const float* __restrict__ V, const float* __restrict__ w,
                              uint4* __restrict__ bfrag) {
    int t = blockIdx.x * blockDim.x + threadIdx.x;
    if (t >= KT_TOTAL * NT * 64) return;
    int lane = t & 63;
    int tile = t >> 6;
    int nt = tile % NT;
    int kt = tile / NT;
    int n = nt * 16 + (lane & 15);
    int kbase = kt * 32 + (lane >> 4) * 8;
    unsigned short o[8];
#pragma unroll
    for (int j = 0; j < 8; ++j) {
        int k = kbase + j;
        float v = 0.f;
        if (k < VOCAB) {
            if (n < F) {
                v = V[(size_t)k * F + n];
            } else if (n == F) {
                v = w[k];                       // f2bf below -> w_hi
            } else if (n == F + 1) {
                float wv = w[k];
                v = wv - bf2f(f2bf(wv));        // residual -> w_lo
            }
        }
        o[j] = f2bf(v);
    }
    uint4 pk;
    pk.x = (unsigned)o[0] | ((unsigned)o[1] << 16);
    pk.y = (unsigned)o[2] | ((unsigned)o[3] << 16);
    pk.z = (unsigned)o[4] | ((unsigned)o[5] << 16);
    pk.w = (unsigned)o[6] | ((unsigned)o[7] << 16);
    bfrag[t] = pk;
}

// --- kernel 3: split-K MFMA GEMM reading PACKED x (proven R2 structure) ---
// Per lane per round: ONE dword of xb (L2-resident; 4-way broadcast across the
// kb lanes of a row) -> byte kb -> 8 bf16 A-elems via selects. B staged to LDS
// (double-buffered) via global_load_lds; one __syncthreads per round. K-pad
// bits are 0, so there is NO guarded tail anywhere.
__global__ __launch_bounds__(256, 4) void fm_main(const unsigned* __restrict__ xb,
                                                  const uint4* __restrict__ bfrag,
                                                  float* __restrict__ part) {
    __shared__ uint4 bbuf[2][NT * 64];        // 2 x 5120 B
    const int bx = blockIdx.x;
    const int split = bx & (SPLITS - 1);      // XCD bx&7 sees only 2 splits
    const int mblock = bx >> 4;
    const int tid = threadIdx.x;
    const int wave = tid >> 6;
    const int lane = tid & 63;
    const int kb = lane >> 4;                 // 0..3
    const int rowA = mblock * 64 + wave * 16 + (lane & 15);
    const int kt0 = split * NR;
    const unsigned* __restrict__ xp = xb + (size_t)rowA * RDWORDS + kt0;
    const int e0 = (wave << 6) + lane;

    auto stage = [&](int rnd) {               // 320 uint4 (one B-tile) -> bbuf[rnd&1]
        const uint4* src = bfrag + (size_t)(kt0 + rnd) * (NT * 64);
        uint4* dst = bbuf[rnd & 1];
        __builtin_amdgcn_global_load_lds((const AS1 void*)(src + e0),
                                         (AS3 void*)(dst + (wave << 6)), 16, 0, 0);
        if (wave == 0)                        // elems 256..319
            __builtin_amdgcn_global_load_lds((const AS1 void*)(src + 256 + lane),
                                             (AS3 void*)(dst + 256), 16, 0, 0);
    };
    auto unpack = [&](unsigned m) -> s16x8 {  // 8 bits -> 8 bf16 in {0,1}
        uint4 apk;
        apk.x = ((m & 1u)   ? 0x3F80u : 0u) | ((m & 2u)   ? 0x3F800000u : 0u);
        apk.y = ((m & 4u)   ? 0x3F80u : 0u) | ((m & 8u)   ? 0x3F800000u : 0u);
        apk.z = ((m & 16u)  ? 0x3F80u : 0u) | ((m & 32u)  ? 0x3F800000u : 0u);
        apk.w = ((m & 64u)  ? 0x3F80u : 0u) | ((m & 128u) ? 0x3F800000u : 0u);
        return __builtin_bit_cast(s16x8, apk);
    };

    f32x4 acc[NT];
#pragma unroll
    for (int nt = 0; nt < NT; ++nt) acc[nt] = (f32x4){0.f, 0.f, 0.f, 0.f};

    stage(0);
    unsigned cd = xp[0];                      // round-0 dword of this lane's row
    __syncthreads();

    for (int r = 0; r < NR; ++r) {
        unsigned nd = 0;
        if (r + 1 < NR) {                     // issue next round: B tile + x dword
            stage(r + 1);
            nd = xp[r + 1];
        }
        s16x8 af = unpack((cd >> (kb * 8)) & 0xFFu);
        const uint4* bb = bbuf[r & 1];
#pragma unroll
        for (int nt = 0; nt < NT; ++nt) {
            s16x8 bf = __builtin_bit_cast(s16x8, bb[nt * 64 + lane]);
            acc[nt] = __builtin_amdgcn_mfma_f32_16x16x32_bf16(af, bf, acc[nt], 0, 0, 0);
        }
        __syncthreads();
        cd = nd;
    }

    // D layout: row = (lane>>4)*4 + r, col = lane&15 (within the 16x16 tile)
    float* __restrict__ p = part + (size_t)split * BROWS * NCOLS;
    int m0 = mblock * 64 + wave * 16 + kb * 4;
    int c0 = lane & 15;
#pragma unroll
    for (int nt = 0; nt < NT; ++nt)
#pragma unroll
        for (int r = 0; r < 4; ++r)
            p[(size_t)(m0 + r) * NCOLS + nt * 16 + c0] = acc[nt][r];
}

// --- kernel 4: reduce splits, square-sum, add linear term ---
__global__ void fm_reduce(const float* __restrict__ part, const float* __restrict__ gbias,
                          float* __restrict__ out) {
    int b = blockIdx.x * 4 + (threadIdx.x >> 6);
    int lane = threadIdx.x & 63;
    float acc = 0.f;
#pragma unroll
    for (int s = 0; s < SPLITS; ++s)
        acc += part[((size_t)s * BROWS + b) * NCOLS + lane];
    float sq = acc * acc;
    float ex = 0.f;
    if (lane < 16)       ex = part[((size_t)lane * BROWS + b) * NCOLS + F];
    else if (lane < 32)  ex = part[((size_t)(lane - 16) * BROWS + b) * NCOLS + F + 1];
#pragma unroll
    for (int off = 32; off; off >>= 1) {
        sq += __shfl_xor(sq, off, 64);
        ex += __shfl_xor(ex, off, 64);
    }
    if (lane == 0) out[b] = gbias[0] + ex + 0.5f * sq;
}

extern "C" void kernel_launch(void* const* d_in, const int* in_sizes, int n_in,
                              void* d_out, int out_size, void* d_ws, size_t ws_size,
                              hipStream_t stream) {
    const int*   x     = (const int*)d_in[0];
    const float* V     = (const float*)d_in[1];
    const float* bias  = (const float*)d_in[2];
    const float* gbias = (const float*)d_in[3];
    float* out = (float*)d_out;

    // workspace layout
    char* ws = (char*)d_ws;
    unsigned* xbw = (unsigned*)ws;                              // 25,690,112 B
    uint4* bfrag  = (uint4*)(ws + (size_t)BROWS * RDWORDS * 4); //  8,028,160 B
    float* w      = (float*)(ws + (size_t)BROWS * RDWORDS * 4 + (size_t)KT_TOTAL * NT * 64 * 16);
    float* part   = (float*)(ws + (size_t)BROWS * RDWORDS * 4 + (size_t)KT_TOTAL * NT * 64 * 16
                             + (size_t)KPAD * 4);               // 20,971,520 B
    // total ~= 54.9 MB

    fm_pack<<<(BROWS * SPANS) / 4, 256, 0, stream>>>(x, xbw);
    fm_prep_w<<<(KPAD + 255) / 256, 256, 0, stream>>>(V, bias, w);
    fm_prep_bfrag<<<(KT_TOTAL * NT * 64 + 255) / 256, 256, 0, stream>>>(V, w, bfrag);
    fm_main<<<(BROWS / 64) * SPLITS, 256, 0, stream>>>(xbw, bfrag, part);
    fm_reduce<<<BROWS / 4, 256, 0, stream>>>(part, gbias, out);
}